// Round 1
// 120.802 us; speedup vs baseline: 1.1133x; 1.1133x over previous
//
#include <hip/hip_runtime.h>
#include <hip/hip_bf16.h>
#include <math.h>

// HIR rainfall-runoff scan — tolerance-bracketed time-chunking + exact fixup.
//
// V2 changes vs previous best (134.5 us):
//  * step math restructured for critical-path latency: dependent chain cut
//    from ~12 VALU ops to 6 (min -> fma -> exp2 -> min -> mul -> fma).
//      - COEFF folded into exponent: cap = exp2(fma(c2, S, log2(COEFF)))
//      - t2 = RMO*(1-k1*S), SMF = (1-k2*S)*t2  => s2 = fma(v, u*RMO, S-ETS)
//      - lower clamp on S dropped (provably slack: ETS <= k3*S <= 0.2*S
//        since SMSC >= 50, so s2 >= 0.8*S >= 0 inductively from S0 = 0)
//      - gw' = fma(1-RecK, gw, RECnew)  (1-op gw chain)
//      - Q = (INR - w) + BAS   where w = u*RMO  (== IRUN + SRUN + BAS)
//    At 1 wave/SIMD this moves pass1 from latency-bound (~46% VALUBusy) to
//    issue-bound.
//  * pass2 parallelized: one thread per (row, chunk) instead of one thread
//    per row serializing over all chunks. Merged chunks exit immediately;
//    an unmerged chunk walks back to the nearest merged predecessor's stored
//    state (same semantics as the old sequential fixup), advances state
//    store-free through intermediate unmerged chunks, then recomputes and
//    stores only its own chunk. 64 waves -> 1024 waves, no wave-wide
//    divergence tax over all 15 chunks.
//
// Q[b,t] (t>=1) = fluxes from carry entering step t; Q[b,0] uses the FINAL
// carry (jnp.roll wraparound) with t=0 inputs (chunk NC-1 owner writes it).

struct P {
    float INSC, SMSC, RecK, g1, lc, k1, k2, k3, c2;
    // g1=1-RecK, lc=log2(COEFF), k1=SUB/SMSC, k2=CRAK/SMSC, k3=10/SMSC,
    // c2=-SQ/SMSC*log2(e)
};

__device__ __forceinline__ P make_params(const float* pINSC, const float* pCOEFF,
                                         const float* pSQ,   const float* pSMSC,
                                         const float* pSUB,  const float* pCRAK,
                                         const float* pRecK) {
    P p;
    p.INSC      = fminf(fmaxf(pINSC[0]  * 5.0f,   0.5f),   5.0f);
    float COEFF = fminf(fmaxf(pCOEFF[0] * 400.0f, 50.0f),  400.0f);
    float SQ    = fminf(fmaxf(pSQ[0]    * 6.0f,   0.0f),   6.0f);
    p.SMSC      = fminf(fmaxf(pSMSC[0]  * 500.0f, 50.0f),  500.0f);
    float SUB   = fminf(fmaxf(pSUB[0],  0.0f), 1.0f);
    float CRAK  = fminf(fmaxf(pCRAK[0], 0.0f), 1.0f);
    p.RecK      = fminf(fmaxf(pRecK[0]  * 0.3f,   0.003f), 0.3f);
    p.g1 = 1.0f - p.RecK;
    p.lc = log2f(COEFF);
    float inv = 1.0f / p.SMSC;
    p.k1 = SUB * inv;
    p.k2 = CRAK * inv;
    p.k3 = 10.0f * inv;
    p.c2 = (-SQ * inv) * 1.44269504088896340736f;
    return p;
}

// Full step with Q. Critical sms chain: fminf -> fmaf -> exp2f -> fminf ->
// mul -> fmaf. Everything else is off-path.
__device__ __forceinline__ float step(float Prec, float PET, float& sms, float& gw, const P& p) {
    float INT  = fminf(fminf(p.INSC, PET), Prec);
    float INR  = Prec - INT;
    float POT  = PET - INT;
    float S    = fminf(sms, p.SMSC);                 // lower clamp provably slack
    float u    = fmaf(-p.k1, S, 1.0f);
    float v    = fmaf(-p.k2, S, 1.0f);
    float ETS  = fminf(POT, p.k3 * S);
    float SmE  = S - ETS;
    float e    = exp2f(fmaf(p.c2, S, p.lc));         // cap = COEFF*2^(c2*S)
    float RMO  = fminf(INR, e);
    float w    = u * RMO;                            // t2 = RMO - SRUN
    float s2   = fmaf(v, w, SmE);                    // S + SMF - ETS
    float SMF  = v * w;
    float REC  = w - SMF;
    float RECnew = REC + fmaxf(s2 - p.SMSC, 0.0f);
    float BAS  = p.RecK * gw;
    float Q    = (INR - w) + BAS;                    // IRUN + SRUN + BAS
    gw  = fmaf(p.g1, gw, RECnew);
    sms = s2;
    return Q;
}

// Warm-up / state-advance step without Q (single exact chain).
__device__ __forceinline__ void stepw(float Prec, float PET, float& sms, float& gw, const P& p) {
    float INT  = fminf(fminf(p.INSC, PET), Prec);
    float INR  = Prec - INT;
    float POT  = PET - INT;
    float S    = fminf(sms, p.SMSC);
    float u    = fmaf(-p.k1, S, 1.0f);
    float v    = fmaf(-p.k2, S, 1.0f);
    float ETS  = fminf(POT, p.k3 * S);
    float SmE  = S - ETS;
    float e    = exp2f(fmaf(p.c2, S, p.lc));
    float RMO  = fminf(INR, e);
    float w    = u * RMO;
    float s2   = fmaf(v, w, SmE);
    float SMF  = v * w;
    float REC  = w - SMF;
    float RECnew = REC + fmaxf(s2 - p.SMSC, 0.0f);
    gw  = fmaf(p.g1, gw, RECnew);
    sms = s2;
}

// Dual-bracket warm-up step: hi chain carries gw; lo chain is sms-only.
__device__ __forceinline__ void dstep(float Prec, float PET,
                                      float& slo, float& shi, float& gw, const P& p) {
    float INT = fminf(fminf(p.INSC, PET), Prec);
    float INR = Prec - INT;
    float POT = PET - INT;
    {   // hi + gw
        float S    = fminf(shi, p.SMSC);
        float u    = fmaf(-p.k1, S, 1.0f);
        float v    = fmaf(-p.k2, S, 1.0f);
        float ETS  = fminf(POT, p.k3 * S);
        float SmE  = S - ETS;
        float e    = exp2f(fmaf(p.c2, S, p.lc));
        float RMO  = fminf(INR, e);
        float w    = u * RMO;
        float s2   = fmaf(v, w, SmE);
        float SMF  = v * w;
        float REC  = w - SMF;
        float RECnew = REC + fmaxf(s2 - p.SMSC, 0.0f);
        gw  = fmaf(p.g1, gw, RECnew);
        shi = s2;
    }
    {   // lo, sms only
        float S    = fminf(slo, p.SMSC);
        float u    = fmaf(-p.k1, S, 1.0f);
        float v    = fmaf(-p.k2, S, 1.0f);
        float ETS  = fminf(POT, p.k3 * S);
        float SmE  = S - ETS;
        float e    = exp2f(fmaf(p.c2, S, p.lc));
        float RMO  = fminf(INR, e);
        float w    = u * RMO;
        slo = fmaf(v, w, SmE);
    }
}

#define MERGE_TOL 0.75f

template<int T, int NC, int W>
__global__ __launch_bounds__(64, 1)
void hir_pass1(const float* __restrict__ inputs,
               const float* __restrict__ pINSC,  const float* __restrict__ pCOEFF,
               const float* __restrict__ pSQ,    const float* __restrict__ pSMSC,
               const float* __restrict__ pSUB,   const float* __restrict__ pCRAK,
               const float* __restrict__ pRecK,
               float* __restrict__ out, float4* __restrict__ st, int B)
{
    int gid = blockIdx.x * blockDim.x + threadIdx.x;
    int b = gid % B;            // consecutive lanes -> consecutive rows
    int c = gid / B;            // wave-uniform (B % 64 == 0)
    if (c >= NC) return;

    P p = make_params(pINSC, pCOEFF, pSQ, pSMSC, pSUB, pCRAK, pRecK);

    const float4* __restrict__ rp = (const float4*)(inputs + (size_t)b * (2 * T));
    float* __restrict__ orow = out + (size_t)b * T;

    constexpr int CH = T / NC;             // 64 steps
    const int i1 = (c * CH) >> 1;          // first main float4 index
    int i0 = i1 - (W >> 1);                // warm-up start (W/2 float4s)
    const bool exact = (i0 <= 0);
    if (i0 < 0) i0 = 0;

    float slo = 0.0f, shi = exact ? 0.0f : p.SMSC, gw = 0.0f;

    // ---- Warm-up: depth-2 pipeline of 4-float4 batches (8 steps each) ----
    const int nwb = (i1 - i0) >> 2;        // warm-up batches (count % 4 == 0)
    if (nwb > 0) {
        float4 A[4], Bq[4], C[4];
        #pragma unroll
        for (int j = 0; j < 4; ++j) A[j] = rp[i0 + j];
        {
            int k1b = (1 < nwb) ? 1 : 0;
            #pragma unroll
            for (int j = 0; j < 4; ++j) Bq[j] = rp[i0 + 4 * k1b + j];
        }
        if (exact) {
            for (int k = 0; k < nwb; ++k) {
                int kn = (k + 2 < nwb) ? (k + 2) : (nwb - 1);
                #pragma unroll
                for (int j = 0; j < 4; ++j) C[j] = rp[i0 + 4 * kn + j];
                #pragma unroll
                for (int j = 0; j < 4; ++j) {
                    stepw(A[j].x, A[j].y, shi, gw, p);
                    stepw(A[j].z, A[j].w, shi, gw, p);
                }
                #pragma unroll
                for (int j = 0; j < 4; ++j) { A[j] = Bq[j]; Bq[j] = C[j]; }
            }
            slo = shi;
        } else {
            for (int k = 0; k < nwb; ++k) {
                int kn = (k + 2 < nwb) ? (k + 2) : (nwb - 1);
                #pragma unroll
                for (int j = 0; j < 4; ++j) C[j] = rp[i0 + 4 * kn + j];
                #pragma unroll
                for (int j = 0; j < 4; ++j) {
                    dstep(A[j].x, A[j].y, slo, shi, gw, p);
                    dstep(A[j].z, A[j].w, slo, shi, gw, p);
                }
                #pragma unroll
                for (int j = 0; j < 4; ++j) { A[j] = Bq[j]; Bq[j] = C[j]; }
            }
        }
    }
    const bool merged = exact || ((shi - slo) <= MERGE_TOL);
    float sms = exact ? shi : (0.5f * (slo + shi));

    // ---- Main chunk: 32 float4s, same depth-2 pipeline, store Q pairs ----
    {
        constexpr int nmb = (CH / 2) / 4;  // 8 batches
        float4 A[4], Bq[4], C[4];
        #pragma unroll
        for (int j = 0; j < 4; ++j) A[j] = rp[i1 + j];
        #pragma unroll
        for (int j = 0; j < 4; ++j) Bq[j] = rp[i1 + 4 + j];
        for (int k = 0; k < nmb; ++k) {
            int kn = (k + 2 < nmb) ? (k + 2) : (nmb - 1);
            #pragma unroll
            for (int j = 0; j < 4; ++j) C[j] = rp[i1 + 4 * kn + j];
            int ibase = i1 + 4 * k;
            #pragma unroll
            for (int j = 0; j < 4; ++j) {
                float qa = step(A[j].x, A[j].y, sms, gw, p);
                float qb = step(A[j].z, A[j].w, sms, gw, p);
                if (c == 0 && k == 0 && j == 0) {
                    orow[1] = qb;          // t=0 owned by the c=NC-1 path
                } else {
                    ((float2*)orow)[ibase + j] = make_float2(qa, qb);
                }
            }
            #pragma unroll
            for (int j = 0; j < 4; ++j) { A[j] = Bq[j]; Bq[j] = C[j]; }
        }
    }

    st[(size_t)c * B + b] = make_float4(sms, gw, merged ? 1.0f : 0.0f, 0.0f);

    if (c == NC - 1) {
        float4 f0 = rp[0];
        float ss = sms, gg = gw;
        orow[0] = step(f0.x, f0.y, ss, gg, p);
    }
}

// Parallel fixup: one thread per (row, chunk). Merged chunks exit after one
// coalesced st read. An unmerged chunk c walks back to the nearest merged
// predecessor m (chunk 0 is always exact => merged, so m exists), advances
// state store-free through chunks m+1..c-1 (those chunks' own threads write
// their outputs), then recomputes chunk c with stores. Semantically identical
// to the old sequential per-row fixup: merged states are accepted as-is in
// both versions.
template<int T, int NC>
__global__ __launch_bounds__(64, 1)
void hir_pass2(const float* __restrict__ inputs,
               const float* __restrict__ pINSC,  const float* __restrict__ pCOEFF,
               const float* __restrict__ pSQ,    const float* __restrict__ pSMSC,
               const float* __restrict__ pSUB,   const float* __restrict__ pCRAK,
               const float* __restrict__ pRecK,
               float* __restrict__ out, const float4* __restrict__ st, int B)
{
    int gid = blockIdx.x * blockDim.x + threadIdx.x;
    int b = gid % B;
    int c = gid / B;
    if (c >= NC) return;

    float4 sc = st[(size_t)c * B + b];
    if (sc.z != 0.0f) return;              // merged -> nothing to fix

    P p = make_params(pINSC, pCOEFF, pSQ, pSMSC, pSUB, pCRAK, pRecK);
    constexpr int CH = T / NC;

    const float4* __restrict__ rp = (const float4*)(inputs + (size_t)b * (2 * T));
    float* __restrict__ orow = out + (size_t)b * T;

    // Walk back to nearest merged predecessor (c >= 1 here: chunk 0 merged).
    int m = c - 1;
    float4 sm = st[(size_t)m * B + b];
    while (sm.z == 0.0f) { --m; sm = st[(size_t)m * B + b]; }
    float sms = sm.x, gw = sm.y;

    // Advance state through chunks m+1..c-1 (no stores).
    {
        const int ia = ((m + 1) * CH) >> 1;
        const int ib = (c * CH) >> 1;
        if (ia < ib) {
            float4 cur = rp[ia];
            for (int i = ia; i < ib; ++i) {
                int ni = (i + 1 < ib) ? (i + 1) : i;
                float4 nxt = rp[ni];
                stepw(cur.x, cur.y, sms, gw, p);
                stepw(cur.z, cur.w, sms, gw, p);
                cur = nxt;
            }
        }
    }

    // Recompute chunk c exactly, with stores.
    {
        const int i1 = (c * CH) >> 1;
        const int i2 = ((c + 1) * CH) >> 1;
        float4 cur = rp[i1];
        for (int i = i1; i < i2; ++i) {
            int ni = (i + 1 < i2) ? (i + 1) : i;
            float4 nxt = rp[ni];
            float qa = step(cur.x, cur.y, sms, gw, p);
            float qb = step(cur.z, cur.w, sms, gw, p);
            ((float2*)orow)[i] = make_float2(qa, qb);
            cur = nxt;
        }
    }

    if (c == NC - 1) {                     // rewrite the t=0 wraparound output
        float4 f0 = rp[0];
        float ss = sms, gg = gw;
        orow[0] = step(f0.x, f0.y, ss, gg, p);
    }
}

// Fallback: monolithic sequential (odd shapes / tiny workspace).
template<int T>
__global__ __launch_bounds__(64, 1)
void hir_scan_kernel(const float* __restrict__ inputs,
                     const float* __restrict__ pINSC,  const float* __restrict__ pCOEFF,
                     const float* __restrict__ pSQ,    const float* __restrict__ pSMSC,
                     const float* __restrict__ pSUB,   const float* __restrict__ pCRAK,
                     const float* __restrict__ pRecK,
                     float* __restrict__ out, int B)
{
    int b = blockIdx.x * blockDim.x + threadIdx.x;
    if (b >= B) return;
    P p = make_params(pINSC, pCOEFF, pSQ, pSMSC, pSUB, pCRAK, pRecK);
    const float4* __restrict__ rp = (const float4*)(inputs + (size_t)b * (2 * T));
    float* __restrict__ orow = out + (size_t)b * T;
    float sms = 0.0f, gw = 0.0f;
    float4 cur = rp[0];
    const float P0 = cur.x, E0 = cur.y;
    constexpr int NI = T / 2;
    for (int i = 0; i < NI; ++i) {
        int ni = (i + 1 < NI) ? (i + 1) : i;
        float4 nxt = rp[ni];
        float qa = step(cur.x, cur.y, sms, gw, p);
        float qb = step(cur.z, cur.w, sms, gw, p);
        if (i == 0) { orow[1] = qb; }
        else        { ((float2*)orow)[i] = make_float2(qa, qb); }
        cur = nxt;
    }
    float ss = sms, gg = gw;
    orow[0] = step(P0, E0, ss, gg, p);
}

extern "C" void kernel_launch(void* const* d_in, const int* in_sizes, int n_in,
                              void* d_out, int out_size, void* d_ws, size_t ws_size,
                              hipStream_t stream) {
    (void)n_in; (void)out_size;
    constexpr int T  = 1024;
    constexpr int NC = 16;    // chunks (CH=64)
    constexpr int W  = 320;   // warm-up steps: expected gap ~250*e^(-.0201*320)~0.4
    const float* inputs = (const float*)d_in[0];
    const float* INSC   = (const float*)d_in[1];
    const float* COEFF  = (const float*)d_in[2];
    const float* SQ     = (const float*)d_in[3];
    const float* SMSC   = (const float*)d_in[4];
    const float* SUB    = (const float*)d_in[5];
    const float* CRAK   = (const float*)d_in[6];
    const float* RecK   = (const float*)d_in[7];
    float* out = (float*)d_out;

    int B = in_sizes[0] / (2 * T);            // 4096 for the reference shape
    size_t need = (size_t)B * NC * sizeof(float4);

    if (ws_size < need || (B % 64) != 0) {
        int blocks = (B + 63) / 64;
        hir_scan_kernel<T><<<dim3(blocks), dim3(64), 0, stream>>>(
            inputs, INSC, COEFF, SQ, SMSC, SUB, CRAK, RecK, out, B);
        return;
    }

    float4* st = (float4*)d_ws;
    long total = (long)B * NC;                // 65536 threads = 1024 waves
    int blocks1 = (int)((total + 63) / 64);
    hir_pass1<T, NC, W><<<dim3(blocks1), dim3(64), 0, stream>>>(
        inputs, INSC, COEFF, SQ, SMSC, SUB, CRAK, RecK, out, st, B);
    int blocks2 = (int)((total + 63) / 64);
    hir_pass2<T, NC><<<dim3(blocks2), dim3(64), 0, stream>>>(
        inputs, INSC, COEFF, SQ, SMSC, SUB, CRAK, RecK, out, st, B);
}